// Round 14
// baseline (170.924 us; speedup 1.0000x reference)
//
#include <hip/hip_runtime.h>

typedef unsigned short u16;
typedef unsigned int u32;
typedef __attribute__((ext_vector_type(4))) float f32x4;
typedef _Float16 f16;
typedef __attribute__((ext_vector_type(2))) f16 h2;
typedef __attribute__((ext_vector_type(8))) f16 h8;

#define NAG 8      // agents per episode
#define EPB 4      // episodes per block
#define NAGB 32    // agents per block
#define FIN 64
#define MDIM 64
#define NACT 10
#define EPG 56     // edges per episode = 8*7
#define NTOT 32768 // B*A
#define ABP 72     // padded A-row for s_xb/s_hidb/s_hgb (144 B)
#define XLS 296    // u16 stride per agent row of xl/xr (148 dw = 20 mod 32: conflict-free)
#define XHS 72     // u16 stride per head within a row

// uraw union (37888 B):
//  ph2-3 : f16 xl (32*296 u16 = 18944 B, bytes 0..18943) + f16 xr (bytes 18944..37887)
//  ph5   : xl still live; s_hgb alias at bytes 25600..30207 (xr dead)
//  ph6-9 : f32 rz[32][132] (0..16895) + f16 hn[32][68] (16896..21247) + f16 inn[32][68]
//          (21248..25599) + f16 ln[32][72] (25600..30207, written ph7 after s_hgb dead)
#define U_XR  9472           // u16 offset of xr
#define U_RZ  0              // f32 idx, stride 132
#define U_HNH 8448           // u16 idx (f16 hn), stride 68
#define U_INB 10624          // u16 idx (f16 inn), stride 68
#define U_HG  12800          // u16 idx of s_hgb alias (byte 25600)
#define U_LNH 12800          // u16 idx of f16 hln (reuses s_hgb region), stride 72

__device__ __forceinline__ u16 f2h(float f) {
  f16 h = (f16)f; u16 u; __builtin_memcpy(&u, &h, 2); return u;
}
__device__ __forceinline__ float h2f(u16 u) {
  f16 h; __builtin_memcpy(&h, &u, 2); return (float)h;
}
// pack two f32 -> one dword of 2 f16 (v_cvt_pkrtz_f16_f32)
__device__ __forceinline__ u32 pkh2(float a, float b) {
#if __has_builtin(__builtin_amdgcn_cvt_pkrtz)
  auto r = __builtin_amdgcn_cvt_pkrtz(a, b);   // __fp16 ext_vector(2)
  u32 u; __builtin_memcpy(&u, &r, 4); return u;
#else
  return (u32)f2h(a) | ((u32)f2h(b) << 16);
#endif
}
// convert 8 consecutive f32 -> h8 fragment (4 cvt_pkrtz)
__device__ __forceinline__ h8 ld8h(const float* __restrict__ p) {
  f32x4 a = *(const f32x4*)p;
  f32x4 b = *(const f32x4*)(p + 4);
  u32 v[4] = { pkh2(a[0], a[1]), pkh2(a[2], a[3]), pkh2(b[0], b[1]), pkh2(b[2], b[3]) };
  h8 r; __builtin_memcpy(&r, v, 16); return r;
}

union H8u { h8 v; h2 p[4]; };

__device__ __forceinline__ h8 lrelu8(h8 m) {
  h8 s = m * (f16)0.2f;
#if __has_builtin(__builtin_elementwise_max)
  return __builtin_elementwise_max(m, s);   // v_pk_max_f16
#else
  h8 r;
#pragma unroll
  for (int i = 0; i < 8; i++) r[i] = (m[i] > s[i]) ? m[i] : s[i];
  return r;
#endif
}

// f32 accumulate of f16 pair product
#if __has_builtin(__builtin_amdgcn_fdot2)
__device__ __forceinline__ float dotacc(h2 a, h2 b, float c) {
  return __builtin_amdgcn_fdot2(a, b, c, false);   // v_dot2_f32_f16
}
#else
__device__ __forceinline__ float dotacc(h2 a, h2 b, float c) {
  c += (float)a[0] * (float)b[0];
  c += (float)a[1] * (float)b[1];
  return c;
}
#endif

__global__ __launch_bounds__(512, 6) void gnn_rnn_kernel(
    const float* __restrict__ x, const float* __restrict__ edge_attr,
    const float* __restrict__ hidden,
    const float* __restrict__ Wl, const float* __restrict__ Wr,
    const float* __restrict__ W_ih, const float* __restrict__ W_hh,
    const float* __restrict__ bl, const float* __restrict__ br,
    const float* __restrict__ We, const float* __restrict__ be,
    const float* __restrict__ att, const float* __restrict__ bias_g,
    const float* __restrict__ b_ih, const float* __restrict__ b_hh,
    const float* __restrict__ ln_g, const float* __restrict__ ln_b,
    const float* __restrict__ Wq, const float* __restrict__ bq,
    float* __restrict__ d_out)
{
  __shared__ __align__(16) char uraw[37888];
  __shared__ __align__(16) u16 s_xb[NAGB * ABP];    // x f16 frags (4608 B)
  __shared__ __align__(16) u16 s_al[NAGB * 4 * 8];  // f16 exp-numerators [a32][h][src], 2048 B
  __shared__ __align__(16) u16 s_hidb[NAGB * ABP];  // hidden f16 frags (4608 B)
  __shared__ __align__(16) u16 s_w0h[256], s_w1h[256], s_w2h[256], s_atth[256]; // f16, [h][64]

  u16*   uXL  = (u16*)uraw;
  u16*   uXR  = (u16*)uraw + U_XR;
  u16*   uHn  = (u16*)uraw + U_HNH;
  u16*   uInn = (u16*)uraw + U_INB;
  u16*   s_hgb = (u16*)uraw + U_HG;     // h_gnn f16 frags (alias in dead xr region)
  u16*   uLnH = (u16*)uraw + U_LNH;     // f16 hln (reuses s_hgb region after barrier D)
  float* uF   = (float*)uraw;

  const int t = threadIdx.x;   // 0..511 (8 waves)
  const int b = blockIdx.x;    // 4-episode group
  const int L = t & 63;        // lane
  const int w = t >> 6;        // wave id 0..7
  const int q = L >> 4;        // quad within wave
  const int wrow = L & 15;     // weight-fragment row within 16-row tile
  const int kc = (L >> 4) * 8; // weight-fragment col base within 32-col half

  // ---------- Phase 1: stage inputs (float4/thread, f16) + small weights; edge_attr ----------
  {
    const float4 xv = ((const float4*)(x + b * (NAGB * FIN)))[t];        // 2048 floats
    const float4 hv = ((const float4*)(hidden + b * (NAGB * MDIM)))[t];
    const int a = t >> 4, m = (t * 4) & 63;
    u32 px[2] = { pkh2(xv.x, xv.y), pkh2(xv.z, xv.w) };
    u32 ph[2] = { pkh2(hv.x, hv.y), pkh2(hv.z, hv.w) };
    *(uint2*)&s_xb[a * ABP + m]   = *(uint2*)px;
    *(uint2*)&s_hidb[a * ABP + m] = *(uint2*)ph;
    if (t < 256) {
      s_w0h[t]  = f2h(We[t * 3]);
      s_w1h[t]  = f2h(We[t * 3 + 1]);
      s_w2h[t]  = f2h(We[t * 3 + 2]);
      s_atth[t] = f2h(att[t]);
    }
  }
  const int h3 = w >> 1, epa = w & 1;   // phase-3 task: wave = (head, ep-pair {epa, epa+2})
  float eaA0 = 0.f, eaA1 = 0.f, eaA2 = 0.f, eaB0 = 0.f, eaB1 = 0.f, eaB2 = 0.f;
  if (L < EPG) {   // prefetch edge attrs for both episodes of this wave (L2-hot)
    const float* eb = edge_attr + b * (EPB * EPG * 3) + epa * (EPG * 3) + L * 3;
    eaA0 = eb[0]; eaA1 = eb[1]; eaA2 = eb[2];
    eaB0 = eb[2 * EPG * 3]; eaB1 = eb[2 * EPG * 3 + 1]; eaB2 = eb[2 * EPG * 3 + 2];
  }
  __syncthreads();

  // ---------- Phase 2 (f16 MFMA, swapped operands): inline weight convert ----------
  {
    const int g = w & 1;                 // agent group (agents g*16 .. g*16+15)
    const int arow = g * 16 + wrow;
    h8 af0 = *(const h8*)&s_xb[arow * ABP + q * 8];
    h8 af1 = *(const h8*)&s_xb[arow * ABP + 32 + q * 8];
#pragma unroll 2
    for (int i = 0; i < 8; i++) {
      const int T = (w >> 1) * 8 + i;             // 0..31 per group
      const float* Wp = (T < 16) ? (Wl + (T * 16 + wrow) * 64)
                                 : (Wr + ((T - 16) * 16 + wrow) * 64);
      h8 wf0 = ld8h(Wp + kc);                     // ks=0 fragment (L2-broadcast-hot)
      h8 wf1 = ld8h(Wp + 32 + kc);                // ks=1 fragment
      f32x4 acc = {0.f, 0.f, 0.f, 0.f};
      acc = __builtin_amdgcn_mfma_f32_16x16x32_f16(wf0, af0, acc, 0, 0, 0);
      acc = __builtin_amdgcn_mfma_f32_16x16x32_f16(wf1, af1, acc, 0, 0, 0);
      const int Tm = T & 15;
      const int h = Tm >> 2;
      const int gcb = Tm * 16 + q * 4;            // 4 consecutive out-dims
      const int d0 = (Tm & 3) * 16 + q * 4;
      f32x4 bias4;
      if (T < 16) bias4 = *(const f32x4*)(bl + gcb);
      else        bias4 = *(const f32x4*)(br + gcb) + *(const f32x4*)(be + gcb);
      f32x4 v = acc + bias4;
      u32 pk2[2] = { pkh2(v[0], v[1]), pkh2(v[2], v[3]) };
      u16* dst = (T < 16 ? uXL : uXR) + arow * XLS + h * XHS + d0;
      *(uint2*)dst = *(uint2*)pk2;
    }
  }
  __syncthreads();   // A: xl/xr ready

  // ---------- Phase 3: edge logits + exp (max-free) — wave = (head, 2 episodes) ----------
  {
    if (L < EPG) {
      const int e = L;
      const int s = e / 7, k = e % 7;
      const int j = k + (k >= s ? 1 : 0);     // dst agent
      const f16 a00 = (f16)eaA0, a01 = (f16)eaA1, a02 = (f16)eaA2;
      const f16 a10 = (f16)eaB0, a11 = (f16)eaB1, a12 = (f16)eaB2;
      const int epA = epa, epB = epa + 2;
      const u16* xlp0 = uXL + (epA * 8 + s) * XLS + h3 * XHS;
      const u16* xrp0 = uXR + (epA * 8 + j) * XLS + h3 * XHS;
      const u16* xlp1 = uXL + (epB * 8 + s) * XLS + h3 * XHS;
      const u16* xrp1 = uXR + (epB * 8 + j) * XLS + h3 * XHS;
      const u16* w0p = s_w0h + h3 * 64;    // wave-uniform -> LDS broadcast
      const u16* w1p = s_w1h + h3 * 64;
      const u16* w2p = s_w2h + h3 * 64;
      const u16* atp = s_atth + h3 * 64;
      float lgA0 = 0.f, lgB0 = 0.f, lgA1 = 0.f, lgB1 = 0.f;
#pragma unroll 2
      for (int kq = 0; kq < 8; kq++) {
        H8u w0, w1, w2, at, x0, r0, x1, r1, m0, m1;
        w0.v = *(const h8*)(w0p + kq * 8);
        w1.v = *(const h8*)(w1p + kq * 8);
        w2.v = *(const h8*)(w2p + kq * 8);
        at.v = *(const h8*)(atp + kq * 8);
        x0.v = *(const h8*)(xlp0 + kq * 8);
        r0.v = *(const h8*)(xrp0 + kq * 8);
        x1.v = *(const h8*)(xlp1 + kq * 8);
        r1.v = *(const h8*)(xrp1 + kq * 8);
        m0.v = x0.v + r0.v + w0.v * a00 + w1.v * a01 + w2.v * a02;  // pk_add/pk_fma
        m0.v = lrelu8(m0.v);
        m1.v = x1.v + r1.v + w0.v * a10 + w1.v * a11 + w2.v * a12;
        m1.v = lrelu8(m1.v);
        lgA0 = dotacc(m0.p[0], at.p[0], lgA0);
        lgB0 = dotacc(m0.p[1], at.p[1], lgB0);
        lgA0 = dotacc(m0.p[2], at.p[2], lgA0);
        lgB0 = dotacc(m0.p[3], at.p[3], lgB0);
        lgA1 = dotacc(m1.p[0], at.p[0], lgA1);
        lgB1 = dotacc(m1.p[1], at.p[1], lgB1);
        lgA1 = dotacc(m1.p[2], at.p[2], lgA1);
        lgB1 = dotacc(m1.p[3], at.p[3], lgB1);
      }
      // max-free softmax numerators: logits are O(+-3) (0.05-scaled weights), exp safe
      s_al[((epa * 8 + j) * 4 + h3) * 8 + s]       = f2h(__expf(lgA0 + lgB0));
      s_al[(((epa + 2) * 8 + j) * 4 + h3) * 8 + s] = f2h(__expf(lgA1 + lgB1));
    } else {
      const int j2 = L - EPG;    // lanes 56..63: zero the diagonal (s == j) slots
      s_al[((epa * 8 + j2) * 4 + h3) * 8 + j2]       = 0;
      s_al[(((epa + 2) * 8 + j2) * 4 + h3) * 8 + j2] = 0;
    }
  }
  __syncthreads();   // B: numerators ready; xr dead

  // ---------- Phase 5: aggregate (packed f16), 1 task/thread, normalize, ReLU ----------
  {
    const int ep = t >> 7, jj = (t >> 4) & 7, dq = t & 15;   // 32 agents x 16 col-quads
    const int a32 = ep * 8 + jj;
    float acc[4] = {0.f, 0.f, 0.f, 0.f};
#pragma unroll
    for (int h = 0; h < 4; h++) {
      H8u av;
      av.v = *(const h8*)&s_al[(a32 * 4 + h) * 8];   // 8 numerators (diag = 0)
      h2 d2 = (av.p[0] + av.p[1]) + (av.p[2] + av.p[3]);
      float den = (float)d2[0] + (float)d2[1];       // softmax denominator
      h2 ah0 = {(f16)0.f, (f16)0.f};
      h2 ah1 = {(f16)0.f, (f16)0.f};
#pragma unroll
      for (int s = 0; s < 8; s++) {
        const u16* xp = uXL + (ep * 8 + s) * XLS + h * XHS + dq * 4;
        uint2 xv = *(const uint2*)xp;
        h2 x01, x23;
        __builtin_memcpy(&x01, &xv.x, 4);
        __builtin_memcpy(&x23, &xv.y, 4);
        f16 al = av.v[s];              // constant idx after unroll
        h2 al2 = {al, al};
        ah0 += al2 * x01;   // v_pk_fma_f16
        ah1 += al2 * x23;
      }
      const float inv = 1.f / den;
      acc[0] += (float)ah0[0] * inv;
      acc[1] += (float)ah0[1] * inv;
      acc[2] += (float)ah1[0] * inv;
      acc[3] += (float)ah1[1] * inv;
    }
    const f32x4 bg = *(const f32x4*)(bias_g + dq * 4);   // global, L2-hot
    float v0 = acc[0] * 0.25f + bg[0];
    float v1 = acc[1] * 0.25f + bg[1];
    float v2 = acc[2] * 0.25f + bg[2];
    float v3 = acc[3] * 0.25f + bg[3];
    u32 pk2[2] = { pkh2(v0 > 0.f ? v0 : 0.f, v1 > 0.f ? v1 : 0.f),
                   pkh2(v2 > 0.f ? v2 : 0.f, v3 > 0.f ? v3 : 0.f) };
    *(uint2*)&s_hgb[a32 * ABP + dq * 4] = *(uint2*)pk2;
  }
  __syncthreads();   // C: h_gnn ready; xl dead -> rz/hn/inn region live

  // ---------- Phase 6 (f16 MFMA, swapped operands): inline weight convert ----------
  {
    const int g = w & 1;
    const int arow = g * 16 + wrow;
    h8 ag0 = *(const h8*)&s_hgb[arow * ABP + q * 8];
    h8 ag1 = *(const h8*)&s_hgb[arow * ABP + 32 + q * 8];
    h8 ah0 = *(const h8*)&s_hidb[arow * ABP + q * 8];
    h8 ah1 = *(const h8*)&s_hidb[arow * ABP + 32 + q * 8];
#pragma unroll 1
    for (int i = 0; i < 3; i++) {
      const int T6 = (w >> 1) * 3 + i;   // 0..11 per group
      const float* Wip = W_ih + (T6 * 16 + wrow) * 64;
      const float* Whp = W_hh + (T6 * 16 + wrow) * 64;
      h8 wi0 = ld8h(Wip + kc);
      h8 wi1 = ld8h(Wip + 32 + kc);
      h8 wh0 = ld8h(Whp + kc);
      h8 wh1 = ld8h(Whp + 32 + kc);
      f32x4 acci = {0.f, 0.f, 0.f, 0.f};
      acci = __builtin_amdgcn_mfma_f32_16x16x32_f16(wi0, ag0, acci, 0, 0, 0);
      acci = __builtin_amdgcn_mfma_f32_16x16x32_f16(wi1, ag1, acci, 0, 0, 0);
      f32x4 acch = {0.f, 0.f, 0.f, 0.f};
      acch = __builtin_amdgcn_mfma_f32_16x16x32_f16(wh0, ah0, acch, 0, 0, 0);
      acch = __builtin_amdgcn_mfma_f32_16x16x32_f16(wh1, ah1, acch, 0, 0, 0);
      const int gcb = T6 * 16 + q * 4;   // 4 consecutive gate dims
      if (T6 < 8) {                      // r,z gates: summed + both biases, b128 store
        f32x4 bsum = *(const f32x4*)(b_ih + gcb) + *(const f32x4*)(b_hh + gcb);
        f32x4 v = acci + acch + bsum;
        *(f32x4*)&uF[U_RZ + arow * 132 + gcb] = v;
      } else {                           // n gate: inn f16, hn f16, packed b64 stores
        f32x4 vi = acci + *(const f32x4*)(b_ih + gcb);
        f32x4 vh = acch + *(const f32x4*)(b_hh + gcb);
        const int off = arow * 68 + (gcb - 128);
        u32 pi[2] = { pkh2(vi[0], vi[1]), pkh2(vi[2], vi[3]) };
        u32 ph[2] = { pkh2(vh[0], vh[1]), pkh2(vh[2], vh[3]) };
        *(uint2*)&uInn[off] = *(uint2*)pi;
        *(uint2*)&uHn[off]  = *(uint2*)ph;
      }
    }
  }
  __syncthreads();   // D: gates ready; s_hgb dead -> hln region writable

  // ---------- Phase 7+8: GRU gates, write h, single-pass in-wave LayerNorm ----------
  {
    const float lng = ln_g[L];   // global, L2-hot
    const float lnb = ln_b[L];
#pragma unroll
    for (int rr = 0; rr < 4; rr++) {
      const int a = w + rr * 8, m = L;   // 0..31
      float rz_r = uF[U_RZ + a * 132 + m];
      float rz_z = uF[U_RZ + a * 132 + 64 + m];
      float inn  = h2f(uInn[a * 68 + m]);
      float hn   = h2f(uHn[a * 68 + m]);
      float hid  = h2f(s_hidb[a * ABP + m]);
      float r = 1.f / (1.f + __expf(-rz_r));
      float z = 1.f / (1.f + __expf(-rz_z));
      float xg = inn + r * hn;
      xg = fminf(fmaxf(xg, -20.f), 20.f);
      float e2 = __expf(2.f * xg);
      float n = (e2 - 1.f) / (e2 + 1.f);
      float hv = (1.f - z) * n + z * hid;
      d_out[NTOT * NACT + (b * NAGB + a) * MDIM + m] = hv;
      float sum = hv, sq = hv * hv;      // two independent shuffle chains
#pragma unroll
      for (int off = 1; off < 64; off <<= 1) {
        sum += __shfl_xor(sum, off, 64);
        sq  += __shfl_xor(sq,  off, 64);
      }
      float mu  = sum * (1.f / 64.f);
      float var = sq * (1.f / 64.f) - mu * mu;
      var = var > 0.f ? var : 0.f;
      uLnH[a * ABP + m] = f2h((hv - mu) * rsqrtf(var + 1e-5f) * lng + lnb);
    }
  }
  __syncthreads();   // E

  // ---------- Phase 9: q = Wq·hln^T via f16 MFMA pairs (waves 0,1), inline Wq ----------
  if (w < 2) {
    const int agent = w * 16 + wrow;
    h8 wq0 = {}, wq1 = {};
    if (wrow < NACT) {                   // rows 10..15 stay zero
      const float* Wqp = Wq + wrow * 64;
      wq0 = ld8h(Wqp + kc);
      wq1 = ld8h(Wqp + 32 + kc);
    }
    h8 ln0 = *(const h8*)(uLnH + agent * ABP + q * 8);
    h8 ln1 = *(const h8*)(uLnH + agent * ABP + 32 + q * 8);
    f32x4 acc = {0.f, 0.f, 0.f, 0.f};
    acc = __builtin_amdgcn_mfma_f32_16x16x32_f16(wq0, ln0, acc, 0, 0, 0);
    acc = __builtin_amdgcn_mfma_f32_16x16x32_f16(wq1, ln1, acc, 0, 0, 0);
    float* qout = d_out + ((size_t)b * NAGB + agent) * NACT;
#pragma unroll
    for (int r = 0; r < 4; r++) {
      const int o = q * 4 + r;           // output row = action index
      if (o < NACT) qout[o] = acc[r] + bq[o];
    }
  }
}

extern "C" void kernel_launch(void* const* d_in, const int* in_sizes, int n_in,
                              void* d_out, int out_size, void* d_ws, size_t ws_size,
                              hipStream_t stream) {
  const int N  = in_sizes[0] / FIN;   // 32768
  const int Bn = N / NAGB;            // 1024 four-episode blocks
  (void)d_ws; (void)ws_size;          // workspace no longer used (no prep kernel)

  gnn_rnn_kernel<<<Bn, 512, 0, stream>>>(
      (const float*)d_in[0], (const float*)d_in[1], (const float*)d_in[2],
      (const float*)d_in[4],   // Wl
      (const float*)d_in[6],   // Wr
      (const float*)d_in[12],  // W_ih
      (const float*)d_in[13],  // W_hh
      (const float*)d_in[5],   // bl
      (const float*)d_in[7],   // br
      (const float*)d_in[8],   // We
      (const float*)d_in[9],   // be
      (const float*)d_in[10],  // att
      (const float*)d_in[11],  // bias_g
      (const float*)d_in[14],  // b_ih
      (const float*)d_in[15],  // b_hh
      (const float*)d_in[16], (const float*)d_in[17],  // ln_g, ln_b
      (const float*)d_in[18], (const float*)d_in[19],  // Wq, bq
      (float*)d_out);
}

// Round 15
// 131.070 us; speedup vs baseline: 1.3041x; 1.3041x over previous
//
#include <hip/hip_runtime.h>

typedef unsigned short u16;
typedef unsigned int u32;
typedef __attribute__((ext_vector_type(8))) short bf16x8;
typedef __attribute__((ext_vector_type(4))) float f32x4;
typedef _Float16 f16;
typedef __attribute__((ext_vector_type(2))) f16 h2;
typedef __attribute__((ext_vector_type(8))) f16 h8;

#define NAG 8      // agents per episode
#define EPB 4      // episodes per block
#define NAGB 32    // agents per block
#define FIN 64
#define MDIM 64
#define NACT 10
#define EPG 56     // edges per episode = 8*7
#define NTOT 32768 // B*A
#define ABP 72     // padded A-row for s_xb/s_hidb/s_hgb (144 B)
#define XLS 296    // u16 stride per agent row of xl/xr (148 dw = 20 mod 32: conflict-free)
#define XHS 72     // u16 stride per head within a row

// uraw union (37888 B):
//  ph2-3 : f16 xl (32*296 u16 = 18944 B, bytes 0..18943) + f16 xr (bytes 18944..37887)
//  ph5   : xl still live; s_hgb alias at bytes 25600..30207 (xr dead)
//  ph6-9 : f32 rz[32][132] (0..16895) + f16 hn[32][68] (16896..21247) + f16 inn[32][68]
//          (21248..25599) + f16 ln[32][72] (25600..30207, written ph7 after s_hgb dead)
#define U_XR  9472           // u16 offset of xr
#define U_RZ  0              // f32 idx, stride 132
#define U_HNH 8448           // u16 idx (f16 hn), stride 68
#define U_INB 10624          // u16 idx (f16 inn), stride 68
#define U_HG  12800          // u16 idx of s_hgb alias (byte 25600)
#define U_LNH 12800          // u16 idx of f16 hln (reuses s_hgb region), stride 72

#define WQOFF 57344          // u16 offset of Wq f16 frag tile in wsB

__device__ __forceinline__ float b2f(u16 u) {
  return __uint_as_float(((unsigned int)u) << 16);
}
__device__ __forceinline__ u16 f2b(float f) {
  unsigned int x = __float_as_uint(f);
  unsigned int r = x + 0x7fffu + ((x >> 16) & 1u);   // RNE; values finite
  return (u16)(r >> 16);
}
__device__ __forceinline__ u16 f2h(float f) {
  f16 h = (f16)f; u16 u; __builtin_memcpy(&u, &h, 2); return u;
}
__device__ __forceinline__ float h2f(u16 u) {
  f16 h; __builtin_memcpy(&h, &u, 2); return (float)h;
}
// pack two f32 -> one dword of 2 f16 (v_cvt_pkrtz_f16_f32)
__device__ __forceinline__ u32 pkh2(float a, float b) {
#if __has_builtin(__builtin_amdgcn_cvt_pkrtz)
  auto r = __builtin_amdgcn_cvt_pkrtz(a, b);   // __fp16 ext_vector(2)
  u32 u; __builtin_memcpy(&u, &r, 4); return u;
#else
  return (u32)f2h(a) | ((u32)f2h(b) << 16);
#endif
}

union H8u { h8 v; h2 p[4]; };

__device__ __forceinline__ h8 lrelu8(h8 m) {
  h8 s = m * (f16)0.2f;
#if __has_builtin(__builtin_elementwise_max)
  return __builtin_elementwise_max(m, s);   // v_pk_max_f16
#else
  h8 r;
#pragma unroll
  for (int i = 0; i < 8; i++) r[i] = (m[i] > s[i]) ? m[i] : s[i];
  return r;
#endif
}

// f32 accumulate of f16 pair product
#if __has_builtin(__builtin_amdgcn_fdot2)
__device__ __forceinline__ float dotacc(h2 a, h2 b, float c) {
  return __builtin_amdgcn_fdot2(a, b, c, false);   // v_dot2_f32_f16
}
#else
__device__ __forceinline__ float dotacc(h2 a, h2 b, float c) {
  c += (float)a[0] * (float)b[0];
  c += (float)a[1] * (float)b[1];
  return c;
}
#endif

// ---------- pre-kernel: repack Wl/Wr/W_ih/W_hh (bf16) + Wq (f16) frag tiles ----------
__global__ __launch_bounds__(256) void prep_weights(
    const float* __restrict__ Wl, const float* __restrict__ Wr,
    const float* __restrict__ Wih, const float* __restrict__ Whh,
    const float* __restrict__ Wq,
    u16* __restrict__ wsB)
{
  const int idx = blockIdx.x * 256 + threadIdx.x;   // 0 .. 57*2*64-1
  if (idx >= 57 * 2 * 64) return;
  const int L  = idx & 63;
  const int ks = (idx >> 6) & 1;
  const int T  = idx >> 7;
  u16 v[8];
  if (T < 56) {
    const float* W; int row0;
    if      (T < 16) { W = Wl;  row0 = T * 16; }
    else if (T < 32) { W = Wr;  row0 = (T - 16) * 16; }
    else if (T < 44) { W = Wih; row0 = (T - 32) * 16; }
    else             { W = Whh; row0 = (T - 44) * 16; }
    const int row = row0 + (L & 15);
    const int k0  = ks * 32 + (L >> 4) * 8;
#pragma unroll
    for (int j = 0; j < 8; j++) v[j] = f2b(W[row * 64 + k0 + j]);
  } else {            // T == 56: Wq f16 frag tile (rows 10..15 zero-padded)
    const int row = L & 15;
    const int k0  = ks * 32 + (L >> 4) * 8;
#pragma unroll
    for (int j = 0; j < 8; j++)
      v[j] = (row < NACT) ? f2h(Wq[row * 64 + k0 + j]) : (u16)0;
  }
  *(bf16x8*)(wsB + (size_t)idx * 8) = *(bf16x8*)v;
}

__global__ __launch_bounds__(512, 6) void gnn_rnn_kernel(
    const float* __restrict__ x, const float* __restrict__ edge_attr,
    const float* __restrict__ hidden,
    const float* __restrict__ bl, const float* __restrict__ br,
    const float* __restrict__ We, const float* __restrict__ be,
    const float* __restrict__ att, const float* __restrict__ bias_g,
    const float* __restrict__ b_ih, const float* __restrict__ b_hh,
    const float* __restrict__ ln_g, const float* __restrict__ ln_b,
    const float* __restrict__ Wq, const float* __restrict__ bq,
    const u16* __restrict__ wsB,
    float* __restrict__ d_out)
{
  __shared__ __align__(16) char uraw[37888];
  __shared__ __align__(16) u16 s_xb[NAGB * ABP];    // x bf16 frags (4608 B)
  __shared__ __align__(16) u16 s_al[NAGB * 4 * 8];  // f16 exp-numerators [a32][h][src], 2048 B
  __shared__ __align__(16) u16 s_hidb[NAGB * ABP];  // hidden bf16 frags (4608 B)
  __shared__ __align__(16) u16 s_w0h[256], s_w1h[256], s_w2h[256], s_atth[256]; // f16, [h][64]

  u16*   uXL  = (u16*)uraw;
  u16*   uXR  = (u16*)uraw + U_XR;
  u16*   uHn  = (u16*)uraw + U_HNH;
  u16*   uInn = (u16*)uraw + U_INB;
  u16*   s_hgb = (u16*)uraw + U_HG;     // h_gnn bf16 frags (alias in dead xr region)
  u16*   uLnH = (u16*)uraw + U_LNH;     // f16 hln (reuses s_hgb region after barrier D)
  float* uF   = (float*)uraw;

  const int t = threadIdx.x;   // 0..511 (8 waves)
  const int b = blockIdx.x;    // 4-episode group
  const int L = t & 63;        // lane
  const int w = t >> 6;        // wave id 0..7
  const int q = L >> 4;        // quad within wave

  // ---------- Phase 1: stage inputs (float4/thread) + small weights; edge_attr ----------
  {
    const float4 xv = ((const float4*)(x + b * (NAGB * FIN)))[t];        // 2048 floats
    const float4 hv = ((const float4*)(hidden + b * (NAGB * MDIM)))[t];
    const int a = t >> 4, m = (t * 4) & 63;
    u16 px[4] = { f2b(xv.x), f2b(xv.y), f2b(xv.z), f2b(xv.w) };
    u16 ph[4] = { f2b(hv.x), f2b(hv.y), f2b(hv.z), f2b(hv.w) };
    *(uint2*)&s_xb[a * ABP + m]   = *(uint2*)px;
    *(uint2*)&s_hidb[a * ABP + m] = *(uint2*)ph;
    if (t < 256) {
      s_w0h[t]  = f2h(We[t * 3]);
      s_w1h[t]  = f2h(We[t * 3 + 1]);
      s_w2h[t]  = f2h(We[t * 3 + 2]);
      s_atth[t] = f2h(att[t]);
    }
  }
  const int h3 = w >> 1, epa = w & 1;   // phase-3 task: wave = (head, ep-pair {epa, epa+2})
  float eaA0 = 0.f, eaA1 = 0.f, eaA2 = 0.f, eaB0 = 0.f, eaB1 = 0.f, eaB2 = 0.f;
  if (L < EPG) {   // prefetch edge attrs for both episodes of this wave (L2-hot)
    const float* eb = edge_attr + b * (EPB * EPG * 3) + epa * (EPG * 3) + L * 3;
    eaA0 = eb[0]; eaA1 = eb[1]; eaA2 = eb[2];
    eaB0 = eb[2 * EPG * 3]; eaB1 = eb[2 * EPG * 3 + 1]; eaB2 = eb[2 * EPG * 3 + 2];
  }
  __syncthreads();

  // ---------- Phase 2 (MFMA, swapped operands): 2 agent-groups x 32 tiles ----------
  {
    const int g = w & 1;                 // agent group (agents g*16 .. g*16+15)
    const int arow = g * 16 + (L & 15);
    bf16x8 af0 = *(const bf16x8*)&s_xb[arow * ABP + q * 8];
    bf16x8 af1 = *(const bf16x8*)&s_xb[arow * ABP + 32 + q * 8];
    const bf16x8* wsBv = (const bf16x8*)wsB;
#pragma unroll
    for (int i = 0; i < 8; i++) {
      const int T = (w >> 1) * 8 + i;             // 0..31 per group
      f32x4 acc = {0.f, 0.f, 0.f, 0.f};
      acc = __builtin_amdgcn_mfma_f32_16x16x32_bf16(wsBv[(T * 2 + 0) * 64 + L], af0, acc, 0, 0, 0);
      acc = __builtin_amdgcn_mfma_f32_16x16x32_bf16(wsBv[(T * 2 + 1) * 64 + L], af1, acc, 0, 0, 0);
      const int Tm = T & 15;
      const int h = Tm >> 2;
      const int gcb = Tm * 16 + q * 4;            // 4 consecutive out-dims
      const int d0 = (Tm & 3) * 16 + q * 4;
      f32x4 bias4;
      if (T < 16) bias4 = *(const f32x4*)(bl + gcb);
      else        bias4 = *(const f32x4*)(br + gcb) + *(const f32x4*)(be + gcb);
      f32x4 v = acc + bias4;
      u32 pk2[2] = { pkh2(v[0], v[1]), pkh2(v[2], v[3]) };
      u16* dst = (T < 16 ? uXL : uXR) + arow * XLS + h * XHS + d0;
      *(uint2*)dst = *(uint2*)pk2;
    }
  }
  __syncthreads();   // A: xl/xr ready

  // ---------- Phase 3: edge logits + exp (max-free) — wave = (head, 2 episodes) ----------
  {
    if (L < EPG) {
      const int e = L;
      const int s = e / 7, k = e % 7;
      const int j = k + (k >= s ? 1 : 0);     // dst agent
      const f16 a00 = (f16)eaA0, a01 = (f16)eaA1, a02 = (f16)eaA2;
      const f16 a10 = (f16)eaB0, a11 = (f16)eaB1, a12 = (f16)eaB2;
      const int epA = epa, epB = epa + 2;
      const u16* xlp0 = uXL + (epA * 8 + s) * XLS + h3 * XHS;
      const u16* xrp0 = uXR + (epA * 8 + j) * XLS + h3 * XHS;
      const u16* xlp1 = uXL + (epB * 8 + s) * XLS + h3 * XHS;
      const u16* xrp1 = uXR + (epB * 8 + j) * XLS + h3 * XHS;
      const u16* w0p = s_w0h + h3 * 64;    // wave-uniform -> LDS broadcast
      const u16* w1p = s_w1h + h3 * 64;
      const u16* w2p = s_w2h + h3 * 64;
      const u16* atp = s_atth + h3 * 64;
      float lgA0 = 0.f, lgB0 = 0.f, lgA1 = 0.f, lgB1 = 0.f;
#pragma unroll 2
      for (int kq = 0; kq < 8; kq++) {
        H8u w0, w1, w2, at, x0, r0, x1, r1, m0, m1;
        w0.v = *(const h8*)(w0p + kq * 8);
        w1.v = *(const h8*)(w1p + kq * 8);
        w2.v = *(const h8*)(w2p + kq * 8);
        at.v = *(const h8*)(atp + kq * 8);
        x0.v = *(const h8*)(xlp0 + kq * 8);
        r0.v = *(const h8*)(xrp0 + kq * 8);
        x1.v = *(const h8*)(xlp1 + kq * 8);
        r1.v = *(const h8*)(xrp1 + kq * 8);
        m0.v = x0.v + r0.v + w0.v * a00 + w1.v * a01 + w2.v * a02;  // pk_add/pk_fma
        m0.v = lrelu8(m0.v);
        m1.v = x1.v + r1.v + w0.v * a10 + w1.v * a11 + w2.v * a12;
        m1.v = lrelu8(m1.v);
        lgA0 = dotacc(m0.p[0], at.p[0], lgA0);
        lgB0 = dotacc(m0.p[1], at.p[1], lgB0);
        lgA0 = dotacc(m0.p[2], at.p[2], lgA0);
        lgB0 = dotacc(m0.p[3], at.p[3], lgB0);
        lgA1 = dotacc(m1.p[0], at.p[0], lgA1);
        lgB1 = dotacc(m1.p[1], at.p[1], lgB1);
        lgA1 = dotacc(m1.p[2], at.p[2], lgA1);
        lgB1 = dotacc(m1.p[3], at.p[3], lgB1);
      }
      // max-free softmax numerators: logits are O(+-3) (0.05-scaled weights), exp safe
      s_al[((epa * 8 + j) * 4 + h3) * 8 + s]       = f2h(__expf(lgA0 + lgB0));
      s_al[(((epa + 2) * 8 + j) * 4 + h3) * 8 + s] = f2h(__expf(lgA1 + lgB1));
    } else {
      const int j2 = L - EPG;    // lanes 56..63: zero the diagonal (s == j) slots
      s_al[((epa * 8 + j2) * 4 + h3) * 8 + j2]       = 0;
      s_al[(((epa + 2) * 8 + j2) * 4 + h3) * 8 + j2] = 0;
    }
  }
  __syncthreads();   // B: numerators ready; xr dead

  // ---------- Phase 5: aggregate (packed f16), 1 task/thread, normalize, ReLU ----------
  {
    const int ep = t >> 7, jj = (t >> 4) & 7, dq = t & 15;   // 32 agents x 16 col-quads
    const int a32 = ep * 8 + jj;
    float acc[4] = {0.f, 0.f, 0.f, 0.f};
#pragma unroll
    for (int h = 0; h < 4; h++) {
      H8u av;
      av.v = *(const h8*)&s_al[(a32 * 4 + h) * 8];   // 8 numerators (diag = 0)
      h2 d2 = (av.p[0] + av.p[1]) + (av.p[2] + av.p[3]);
      float den = (float)d2[0] + (float)d2[1];       // softmax denominator
      h2 ah0 = {(f16)0.f, (f16)0.f};
      h2 ah1 = {(f16)0.f, (f16)0.f};
#pragma unroll
      for (int s = 0; s < 8; s++) {
        const u16* xp = uXL + (ep * 8 + s) * XLS + h * XHS + dq * 4;
        uint2 xv = *(const uint2*)xp;
        h2 x01, x23;
        __builtin_memcpy(&x01, &xv.x, 4);
        __builtin_memcpy(&x23, &xv.y, 4);
        f16 al = av.v[s];              // constant idx after unroll
        h2 al2 = {al, al};
        ah0 += al2 * x01;   // v_pk_fma_f16
        ah1 += al2 * x23;
      }
      const float inv = 1.f / den;
      acc[0] += (float)ah0[0] * inv;
      acc[1] += (float)ah0[1] * inv;
      acc[2] += (float)ah1[0] * inv;
      acc[3] += (float)ah1[1] * inv;
    }
    const f32x4 bg = *(const f32x4*)(bias_g + dq * 4);   // global, L2-hot
    u16 pk[4];
#pragma unroll
    for (int c = 0; c < 4; c++) {
      float v = acc[c] * 0.25f + bg[c];
      pk[c] = f2b(v > 0.f ? v : 0.f);
    }
    *(uint2*)&s_hgb[a32 * ABP + dq * 4] = *(uint2*)pk;
  }
  __syncthreads();   // C: h_gnn ready; xl dead -> rz/hn/inn region live

  // ---------- Phase 6 (MFMA, swapped operands): 2 groups x 12 tiles, 3/wave ----------
  {
    const int g = w & 1;
    const int arow = g * 16 + (L & 15);
    bf16x8 ag0 = *(const bf16x8*)&s_hgb[arow * ABP + q * 8];
    bf16x8 ag1 = *(const bf16x8*)&s_hgb[arow * ABP + 32 + q * 8];
    bf16x8 ah0 = *(const bf16x8*)&s_hidb[arow * ABP + q * 8];
    bf16x8 ah1 = *(const bf16x8*)&s_hidb[arow * ABP + 32 + q * 8];
    const bf16x8* wsBv = (const bf16x8*)wsB;
#pragma unroll
    for (int i = 0; i < 3; i++) {
      const int T6 = (w >> 1) * 3 + i;   // 0..11 per group
      const int Tg = 32 + T6, Th = 44 + T6;
      f32x4 acci = {0.f, 0.f, 0.f, 0.f};
      acci = __builtin_amdgcn_mfma_f32_16x16x32_bf16(wsBv[(Tg * 2 + 0) * 64 + L], ag0, acci, 0, 0, 0);
      acci = __builtin_amdgcn_mfma_f32_16x16x32_bf16(wsBv[(Tg * 2 + 1) * 64 + L], ag1, acci, 0, 0, 0);
      f32x4 acch = {0.f, 0.f, 0.f, 0.f};
      acch = __builtin_amdgcn_mfma_f32_16x16x32_bf16(wsBv[(Th * 2 + 0) * 64 + L], ah0, acch, 0, 0, 0);
      acch = __builtin_amdgcn_mfma_f32_16x16x32_bf16(wsBv[(Th * 2 + 1) * 64 + L], ah1, acch, 0, 0, 0);
      const int gcb = T6 * 16 + q * 4;   // 4 consecutive gate dims
      if (T6 < 8) {                      // r,z gates: summed + both biases, b128 store
        f32x4 bsum = *(const f32x4*)(b_ih + gcb) + *(const f32x4*)(b_hh + gcb);
        f32x4 v = acci + acch + bsum;
        *(f32x4*)&uF[U_RZ + arow * 132 + gcb] = v;
      } else {                           // n gate: inn f16, hn f16, packed b64 stores
        f32x4 vi = acci + *(const f32x4*)(b_ih + gcb);
        f32x4 vh = acch + *(const f32x4*)(b_hh + gcb);
        const int off = arow * 68 + (gcb - 128);
        u32 pi[2] = { pkh2(vi[0], vi[1]), pkh2(vi[2], vi[3]) };
        u32 ph[2] = { pkh2(vh[0], vh[1]), pkh2(vh[2], vh[3]) };
        *(uint2*)&uInn[off] = *(uint2*)pi;
        *(uint2*)&uHn[off]  = *(uint2*)ph;
      }
    }
  }
  __syncthreads();   // D: gates ready; s_hgb dead -> hln region writable

  // ---------- Phase 7+8: GRU gates, write h, single-pass in-wave LayerNorm ----------
  {
    const float lng = ln_g[L];   // global, L2-hot
    const float lnb = ln_b[L];
#pragma unroll
    for (int rr = 0; rr < 4; rr++) {
      const int a = w + rr * 8, m = L;   // 0..31
      float rz_r = uF[U_RZ + a * 132 + m];
      float rz_z = uF[U_RZ + a * 132 + 64 + m];
      float inn  = h2f(uInn[a * 68 + m]);
      float hn   = h2f(uHn[a * 68 + m]);
      float hid  = b2f(s_hidb[a * ABP + m]);
      float r = 1.f / (1.f + __expf(-rz_r));
      float z = 1.f / (1.f + __expf(-rz_z));
      float xg = inn + r * hn;
      xg = fminf(fmaxf(xg, -20.f), 20.f);
      float e2 = __expf(2.f * xg);
      float n = (e2 - 1.f) / (e2 + 1.f);
      float hv = (1.f - z) * n + z * hid;
      d_out[NTOT * NACT + (b * NAGB + a) * MDIM + m] = hv;
      float sum = hv, sq = hv * hv;      // two independent shuffle chains
#pragma unroll
      for (int off = 1; off < 64; off <<= 1) {
        sum += __shfl_xor(sum, off, 64);
        sq  += __shfl_xor(sq,  off, 64);
      }
      float mu  = sum * (1.f / 64.f);
      float var = sq * (1.f / 64.f) - mu * mu;
      var = var > 0.f ? var : 0.f;
      uLnH[a * ABP + m] = f2h((hv - mu) * rsqrtf(var + 1e-5f) * lng + lnb);
    }
  }
  __syncthreads();   // E

  // ---------- Phase 9: q = Wq·hln^T via f16 MFMA pairs (waves 0,1) ----------
  if (w < 2) {
    const int agent = w * 16 + (L & 15);
    const u16* wq = wsB + WQOFF;
    h8 wq0, wq1, ln0, ln1;
    wq0 = *(const h8*)(wq + (size_t)(0 * 64 + L) * 8);
    wq1 = *(const h8*)(wq + (size_t)(1 * 64 + L) * 8);
    ln0 = *(const h8*)(uLnH + agent * ABP + q * 8);
    ln1 = *(const h8*)(uLnH + agent * ABP + 32 + q * 8);
    f32x4 acc = {0.f, 0.f, 0.f, 0.f};
    acc = __builtin_amdgcn_mfma_f32_16x16x32_f16(wq0, ln0, acc, 0, 0, 0);
    acc = __builtin_amdgcn_mfma_f32_16x16x32_f16(wq1, ln1, acc, 0, 0, 0);
    float* qout = d_out + ((size_t)b * NAGB + agent) * NACT;
#pragma unroll
    for (int r = 0; r < 4; r++) {
      const int o = q * 4 + r;           // output row = action index
      if (o < NACT) qout[o] = acc[r] + bq[o];
    }
  }
}

extern "C" void kernel_launch(void* const* d_in, const int* in_sizes, int n_in,
                              void* d_out, int out_size, void* d_ws, size_t ws_size,
                              hipStream_t stream) {
  const int N  = in_sizes[0] / FIN;   // 32768
  const int Bn = N / NAGB;            // 1024 four-episode blocks
  u16* wsB = (u16*)d_ws;              // 57*2*64*8 u16 = 114 KiB

  prep_weights<<<29, 256, 0, stream>>>(
      (const float*)d_in[4],   // Wl
      (const float*)d_in[6],   // Wr
      (const float*)d_in[12],  // W_ih
      (const float*)d_in[13],  // W_hh
      (const float*)d_in[18],  // Wq
      wsB);

  gnn_rnn_kernel<<<Bn, 512, 0, stream>>>(
      (const float*)d_in[0], (const float*)d_in[1], (const float*)d_in[2],
      (const float*)d_in[5],   // bl
      (const float*)d_in[7],   // br
      (const float*)d_in[8],   // We
      (const float*)d_in[9],   // be
      (const float*)d_in[10],  // att
      (const float*)d_in[11],  // bias_g
      (const float*)d_in[14],  // b_ih
      (const float*)d_in[15],  // b_hh
      (const float*)d_in[16], (const float*)d_in[17],  // ln_g, ln_b
      (const float*)d_in[18], (const float*)d_in[19],  // Wq, bq
      wsB, (float*)d_out);
}